// Round 9
// baseline (588.950 us; speedup 1.0000x reference)
//
#include <hip/hip_runtime.h>

#define HASH_SIZE 16384
#define N_LEVELS  12
#define LP        6     // level pairs per point

// LDS-staged dense tables for levels 6,7,8 (res 1024/2048/4096; no hash wrap,
// entries h=0..res+1 so the e1=h+1 read never walks off the end):
//   level 6: off 0,    n=1026
//   level 7: off 1026, n=2050
//   level 8: off 3076, n=4098   -> total 7174 float2 = 57392 B
#define L6_OFF 0
#define L7_OFF 1026
#define L8_OFF 3076
#define LDS_N  7174

typedef float floatx4 __attribute__((ext_vector_type(4)));

// ---------------------------------------------------------------------------
// Kernel A: build paired, level-major gather table in workspace (3 MB, L2-fit).
//   ws4[l*HASH_SIZE + h] = { e0.x, e0.y, e1.x, e1.y }, h1=(h+1)&mask baked in.
// ---------------------------------------------------------------------------
__global__ __launch_bounds__(256) void build_ws_kernel(
    const float* __restrict__ table,   // [HASH_SIZE, N_LEVELS*2]
    float4* __restrict__ ws4)          // [N_LEVELS * HASH_SIZE]
{
    int tid = blockIdx.x * blockDim.x + threadIdx.x;
    if (tid >= N_LEVELS * HASH_SIZE) return;
    int l  = tid >> 14;
    int h  = tid & (HASH_SIZE - 1);
    int h1 = (h + 1) & (HASH_SIZE - 1);
    const float2 e0 = *reinterpret_cast<const float2*>(table + h  * (N_LEVELS * 2) + l * 2);
    const float2 e1 = *reinterpret_cast<const float2*>(table + h1 * (N_LEVELS * 2) + l * 2);
    ws4[tid] = make_float4(e0.x, e0.y, e1.x, e1.y);
}

// ---------------------------------------------------------------------------
// Kernel B: persistent grid; thread = (level-pair p, 4 points).
//   stride % 6 == 0 -> p constant per thread.
//   p=0..2 : levels 0..5  -> global ws4, L1-resident (16 KB footprint)
//   p=3    : levels 6,7   -> LDS
//   p=4    : level 8 LDS, level 9 global (nt)
//   p=5    : levels 10,11 -> global (nt)  [nt: don't thrash L1]
// ---------------------------------------------------------------------------
__global__ __launch_bounds__(768, 6) void hashgrid_lds_kernel(
    const float* __restrict__ x,
    const float4* __restrict__ ws4,
    float* __restrict__ out,           // [BATCH*24] floats
    int quarter)                       // BATCH*6/4, divisible by 6
{
    __shared__ float2 lds2[LDS_N];

    // stage levels 6-8 (e0 halves of ws4 rows = raw table entries)
    for (int i = threadIdx.x; i < LDS_N; i += 768) {
        int l, off;
        if      (i < L7_OFF) { l = 6; off = L6_OFF; }
        else if (i < L8_OFF) { l = 7; off = L7_OFF; }
        else                 { l = 8; off = L8_OFF; }
        float4 e = ws4[l * HASH_SIZE + (i - off)];
        lds2[i] = make_float2(e.x, e.y);
    }
    __syncthreads();

    const int stride = gridDim.x * 768;        // divisible by 6 (512*768)
    int t = blockIdx.x * 768 + threadIdx.x;
    int b = t / LP;
    const int p = t - b * LP;                  // constant across iterations
    const int bstep = stride / LP;
    const int bq = quarter / LP;               // batch/4

    const int   la = 2 * p, lb = la + 1;
    const float resa = (float)(16 << la);
    const float resb = (float)(16 << lb);
    const float4* __restrict__ ga = ws4 + la * HASH_SIZE;
    const float4* __restrict__ gb = ws4 + lb * HASH_SIZE;
    const floatx4* __restrict__ gan = reinterpret_cast<const floatx4*>(ga);
    const floatx4* __restrict__ gbn = reinterpret_cast<const floatx4*>(gb);
    floatx4* __restrict__ out4 = reinterpret_cast<floatx4*>(out);

    for (; t < quarter; t += stride, b += bstep) {
        int   ha[4], hb[4];
        float wa[4], wb[4];
        #pragma unroll
        for (int q = 0; q < 4; ++q) {
            float xc = fminf(fmaxf(x[b + q * bq], 0.0f), 1.0f);
            float pa = xc * resa, pb = xc * resb;
            float fa = floorf(pa), fb = floorf(pb);
            wa[q] = pa - fa;  wb[q] = pb - fb;
            ha[q] = ((int)fa) & (HASH_SIZE - 1);   // identity for l<=9
            hb[q] = ((int)fb) & (HASH_SIZE - 1);
        }

        float4 ea[4], eb[4];
        if (p < 3) {                       // levels 0..5: L1-hot global
            #pragma unroll
            for (int q = 0; q < 4; ++q) { ea[q] = ga[ha[q]]; eb[q] = gb[hb[q]]; }
        } else if (p == 3) {               // levels 6,7: LDS
            #pragma unroll
            for (int q = 0; q < 4; ++q) {
                float2 a0 = lds2[L6_OFF + ha[q]], a1 = lds2[L6_OFF + ha[q] + 1];
                float2 b0 = lds2[L7_OFF + hb[q]], b1 = lds2[L7_OFF + hb[q] + 1];
                ea[q] = make_float4(a0.x, a0.y, a1.x, a1.y);
                eb[q] = make_float4(b0.x, b0.y, b1.x, b1.y);
            }
        } else if (p == 4) {               // level 8: LDS, level 9: global nt
            #pragma unroll
            for (int q = 0; q < 4; ++q) {
                float2 a0 = lds2[L8_OFF + ha[q]], a1 = lds2[L8_OFF + ha[q] + 1];
                ea[q] = make_float4(a0.x, a0.y, a1.x, a1.y);
                floatx4 v = __builtin_nontemporal_load(gbn + hb[q]);
                eb[q] = make_float4(v.x, v.y, v.z, v.w);
            }
        } else {                           // levels 10,11: global nt
            #pragma unroll
            for (int q = 0; q < 4; ++q) {
                floatx4 va = __builtin_nontemporal_load(gan + ha[q]);
                floatx4 vb = __builtin_nontemporal_load(gbn + hb[q]);
                ea[q] = make_float4(va.x, va.y, va.z, va.w);
                eb[q] = make_float4(vb.x, vb.y, vb.z, vb.w);
            }
        }

        #pragma unroll
        for (int q = 0; q < 4; ++q) {
            floatx4 r;
            r.x = (1.0f - wa[q]) * ea[q].x + wa[q] * ea[q].z;
            r.y = (1.0f - wa[q]) * ea[q].y + wa[q] * ea[q].w;
            r.z = (1.0f - wb[q]) * eb[q].x + wb[q] * eb[q].z;
            r.w = (1.0f - wb[q]) * eb[q].y + wb[q] * eb[q].w;
            __builtin_nontemporal_store(r, out4 + t + q * quarter);
        }
    }
}

// ---------------------------------------------------------------------------
// Generic pair kernel (round-5 structure) for batch % 4 != 0.
// ---------------------------------------------------------------------------
__global__ __launch_bounds__(256) void hashgrid_pair_kernel(
    const float* __restrict__ x,
    const float4* __restrict__ ws4,
    float* __restrict__ out,
    int total)                         // BATCH * 6
{
    int t = blockIdx.x * 256 + threadIdx.x;
    if (t >= total) return;
    int b = t / LP;
    int p = t - b * LP;
    float xc = fminf(fmaxf(x[b], 0.0f), 1.0f);

    floatx4 r;
    #pragma unroll
    for (int k = 0; k < 2; ++k) {
        int   lvl = p * 2 + k;
        float res = (float)(16 << lvl);
        float pos = xc * res;
        float fi  = floorf(pos);
        float w   = pos - fi;
        int   h0  = ((int)fi) & (HASH_SIZE - 1);
        float4 e = ws4[lvl * HASH_SIZE + h0];
        float omw = 1.0f - w;
        float r0 = omw * e.x + w * e.z;
        float r1 = omw * e.y + w * e.w;
        if (k == 0) { r.x = r0; r.y = r1; }
        else        { r.z = r0; r.w = r1; }
    }
    __builtin_nontemporal_store(r, reinterpret_cast<floatx4*>(out) + t);
}

// ---------------------------------------------------------------------------
// Fallback (ws too small): direct kernel, known-correct.
// ---------------------------------------------------------------------------
__global__ __launch_bounds__(256) void hashgrid_direct_kernel(
    const float* __restrict__ x,
    const float* __restrict__ table,
    float* __restrict__ out,
    int total)
{
    int idx = blockIdx.x * blockDim.x + threadIdx.x;
    if (idx >= total) return;
    int b = idx / N_LEVELS;
    int l = idx - b * N_LEVELS;
    float xc  = fminf(fmaxf(x[b], 0.0f), 1.0f);
    float res = (float)(16 << l);
    float pos = xc * res;
    float fi  = floorf(pos);
    int   i0  = (int)fi;
    float w   = pos - fi;
    int h0 = i0 & (HASH_SIZE - 1);
    int h1 = (i0 + 1) & (HASH_SIZE - 1);
    const float2 e0 = *reinterpret_cast<const float2*>(table + h0 * (N_LEVELS * 2) + l * 2);
    const float2 e1 = *reinterpret_cast<const float2*>(table + h1 * (N_LEVELS * 2) + l * 2);
    float omw = 1.0f - w;
    float2 rr;
    rr.x = omw * e0.x + w * e1.x;
    rr.y = omw * e0.y + w * e1.y;
    *reinterpret_cast<float2*>(out + (size_t)idx * 2) = rr;
}

extern "C" void kernel_launch(void* const* d_in, const int* in_sizes, int n_in,
                              void* d_out, int out_size, void* d_ws, size_t ws_size,
                              hipStream_t stream) {
    const float* x     = (const float*)d_in[0];
    const float* table = (const float*)d_in[1];
    int batch = in_sizes[0];

    const size_t ws_needed = (size_t)N_LEVELS * HASH_SIZE * sizeof(float4);  // 3 MB

    if (ws_size >= ws_needed) {
        float4* ws4 = (float4*)d_ws;

        int ta = N_LEVELS * HASH_SIZE;
        build_ws_kernel<<<(ta + 255) / 256, 256, 0, stream>>>(table, ws4);

        int total = batch * LP;                    // BATCH * 6
        if ((batch & 3) == 0) {
            int quarter = total >> 2;              // divisible by 6
            // persistent grid: 512 blocks x 768 thr = 393216 (divisible by 6);
            // 2 blocks/CU (57.4 KB LDS each) -> 24 waves/CU.
            hashgrid_lds_kernel<<<512, 768, 0, stream>>>(
                x, ws4, (float*)d_out, quarter);
        } else {
            hashgrid_pair_kernel<<<(total + 255) / 256, 256, 0, stream>>>(
                x, ws4, (float*)d_out, total);
        }
    } else {
        int total = batch * N_LEVELS;
        hashgrid_direct_kernel<<<(total + 255) / 256, 256, 0, stream>>>(
            x, table, (float*)d_out, total);
    }
}